// Round 8
// baseline (195.336 us; speedup 1.0000x reference)
//
#include <hip/hip_runtime.h>

// SelfAttention: B=4, S=4096, E=1024, H=64, single head, causal, p=0.
// I/O fp32, internals bf16 MFMA.
// Round 8: proj_all double-buffered (one barrier per K-step, prefetch hides
// HBM latency; LDS 64 KB, 2 blocks/CU). Attn (R7 structure) unchanged.

using short8 = __attribute__((ext_vector_type(8))) short;
using f32x4  = __attribute__((ext_vector_type(4))) float;

#define MFMA16(A, B, C) __builtin_amdgcn_mfma_f32_16x16x32_bf16((A), (B), (C), 0, 0, 0)

typedef const __attribute__((address_space(1))) void* gas_ptr;
typedef __attribute__((address_space(3))) void*       las_ptr;

__device__ __forceinline__ void gload16(const void* g, void* l) {
    // async global->LDS, 16B/lane, LDS dst = base + lane*16 (wave-uniform base)
    __builtin_amdgcn_global_load_lds((gas_ptr)g, (las_ptr)l, 16, 0, 0);
}

__device__ __forceinline__ unsigned short f2bf(float f) {
    unsigned u = __builtin_bit_cast(unsigned, f);
    u += 0x7fffu + ((u >> 16) & 1u);   // RNE
    return (unsigned short)(u >> 16);
}
__device__ __forceinline__ float bf2f(unsigned short u) {
    unsigned v = ((unsigned)u) << 16;
    return __builtin_bit_cast(float, v);
}

// ---------------------------------------------------------------- transpose + Vt pad fill
__global__ __launch_bounds__(256) void transpose_w(
    const float* __restrict__ Wq,
    const float* __restrict__ Wk,
    const float* __restrict__ Wv,
    unsigned short* __restrict__ Wt,
    unsigned short* __restrict__ Vt)
{
    int o = blockIdx.x * 256 + threadIdx.x;   // 196608 + 262144 total
    if (o < 196608) {
        int my  = o >> 16;
        int rem = o & 65535;
        int h   = rem >> 10;
        int e   = rem & 1023;
        const float* W = (my == 0) ? Wq : (my == 1) ? Wk : Wv;
        Wt[o] = f2bf(W[e * 64 + h]);
    } else {
        int j   = o - 196608;                 // 4 b x 16 rows x 4096
        int b   = j >> 16;
        int rem = j & 65535;
        int h   = 64 + (rem >> 12);
        int s   = rem & 4095;
        Vt[((size_t)(b * 80 + h)) * 4096 + s] = (h == 64) ? 0x3F80 : 0;
    }
}

// ---------------------------------------------------------------- projection
// 512 blocks x 128 thr (2 waves), 32 rows x 192 cols per block, K-loop 1024
// step 64. DOUBLE-BUFFERED LDS-DMA staging: stage(k0+64) issued before
// compute(k0), single barrier per iteration drains it after compute.
__global__ __launch_bounds__(128, 2) void proj_all(
    const float* __restrict__ x,             // [16384][1024] fp32
    const unsigned short* __restrict__ Wt,   // [3][64][1024] bf16
    unsigned short* __restrict__ Qo,         // [16384][64] bf16
    unsigned short* __restrict__ Ko,         // [16384][64] bf16
    unsigned short* __restrict__ Vto)        // [4][80][4096] bf16 (V^T, padded)
{
    const int m0   = blockIdx.x * 32;
    const int tid  = threadIdx.x;
    const int lane = tid & 63;
    const int wv   = tid >> 6;     // 0..1
    const int quad = lane >> 4;
    const int n    = lane & 15;

    __shared__ __align__(16) float xs[2][2][4][64][4];   // 16 KB (buf, wave, j)
    __shared__ __align__(16) short wf[2][24][64][8];     // 48 KB

    const f32x4 zero4 = {0.f, 0.f, 0.f, 0.f};
    f32x4 acc[3][4];
    #pragma unroll
    for (int mt = 0; mt < 3; ++mt)
        #pragma unroll
        for (int nt = 0; nt < 4; ++nt) acc[mt][nt] = zero4;

    const float* xrow = x + (size_t)(m0 + wv * 16 + n) * 1024 + quad * 8;

    auto stage = [&](int k0, int p) {
        #pragma unroll
        for (int j = 0; j < 4; ++j)
            gload16(xrow + k0 + (j >> 1) * 32 + (j & 1) * 4, &xs[p][wv][j][0][0]);
        #pragma unroll
        for (int it = 0; it < 12; ++it) {
            int f  = wv + 2 * it;              // 0..23
            int mt = f >> 3;
            int g  = f & 7;
            int c  = g >> 2, nt = g & 3;
            gload16(Wt + mt * 65536 + (nt * 16 + n) * 1024 + k0 + c * 32 + quad * 8,
                    &wf[p][f][0][0]);
        }
    };

    int p = 0;
    stage(0, 0);
    __syncthreads();

    for (int k0 = 0; k0 < 1024; k0 += 64) {
        if (k0 < 960) stage(k0 + 64, p ^ 1);   // prefetch (drained at barrier)

        f32x4 u0 = *(const f32x4*)(&xs[p][wv][0][lane][0]);
        f32x4 u1 = *(const f32x4*)(&xs[p][wv][1][lane][0]);
        f32x4 u2 = *(const f32x4*)(&xs[p][wv][2][lane][0]);
        f32x4 u3 = *(const f32x4*)(&xs[p][wv][3][lane][0]);
        short8 a0, a1;
        #pragma unroll
        for (int j = 0; j < 4; ++j) {
            a0[j]     = (short)f2bf(u0[j]);
            a0[4 + j] = (short)f2bf(u1[j]);
            a1[j]     = (short)f2bf(u2[j]);
            a1[4 + j] = (short)f2bf(u3[j]);
        }

        #pragma unroll
        for (int mt = 0; mt < 3; ++mt)
            #pragma unroll
            for (int nt = 0; nt < 4; ++nt) {
                acc[mt][nt] = MFMA16(a0, *(const short8*)(&wf[p][mt * 8 + nt][lane][0]),     acc[mt][nt]);
                acc[mt][nt] = MFMA16(a1, *(const short8*)(&wf[p][mt * 8 + 4 + nt][lane][0]), acc[mt][nt]);
            }

        __syncthreads();   // drain prefetch DMA + protect buffers
        p ^= 1;
    }

    #pragma unroll
    for (int nt = 0; nt < 4; ++nt) {
        #pragma unroll
        for (int r = 0; r < 4; ++r) {
            int m = m0 + wv * 16 + quad * 4 + r;
            int h = nt * 16 + n;
            Qo[(size_t)m * 64 + h] = f2bf(acc[0][nt][r]);
            Ko[(size_t)m * 64 + h] = f2bf(acc[1][nt][r]);
            int b = m >> 12, s = m & 4095;
            Vto[((size_t)(b * 80 + h)) * 4096 + s] = f2bf(acc[2][nt][r]);
        }
    }
}

// ---------------------------------------------------------------- attention
// (R7 structure, unchanged) 64-row Q-tile, 2 waves x 32 rows, double-buffered
// K/V staging, one barrier per kt. Fixed-max softmax, rowsum via ones-column.
template <int SPLIT>
__device__ __forceinline__ void attn_body(
    const unsigned short* __restrict__ Q,
    const unsigned short* __restrict__ K,
    const unsigned short* __restrict__ Vt,   // [4][80][4096], row 64 = ones
    float* __restrict__ dst,
    int b, int r0, int ktdiag, int kt0, int kt1)
{
    const int tid  = threadIdx.x;
    const int lane = tid & 63;
    const int wv   = tid >> 6;
    const int quad = lane >> 4;
    const int n    = lane & 15;

    __shared__ __align__(16) short kf[2][8][64][8];            // 16 KB
    __shared__ __align__(16) short vf[2][10][64][8];           // 20 KB
    __shared__ __align__(16) unsigned short pbuf[2][32][72];   // 9 KB

    short8 qa[2][2];
    #pragma unroll
    for (int rg = 0; rg < 2; ++rg) {
        const unsigned short* qp =
            Q + (size_t)(b * 4096 + r0 + wv * 32 + rg * 16 + n) * 64 + quad * 8;
        #pragma unroll
        for (int j = 0; j < 8; ++j) {
            qa[rg][0][j] = (short)f2bf(bf2f(qp[j])      * 0.125f);
            qa[rg][1][j] = (short)f2bf(bf2f(qp[32 + j]) * 0.125f);
        }
    }

    const f32x4 zero4 = {0.f, 0.f, 0.f, 0.f};
    f32x4 oacc[2][5];
    #pragma unroll
    for (int rg = 0; rg < 2; ++rg)
        #pragma unroll
        for (int nt = 0; nt < 5; ++nt) oacc[rg][nt] = zero4;

    const unsigned short* kbase = K  + ((size_t)b * 4096 + n) * 64 + quad * 8;
    const unsigned short* vbase = Vt + ((size_t)b * 80 + n) * 4096 + quad * 8;

    auto stage = [&](int kt, int p) {
        #pragma unroll
        for (int it = 0; it < 9; ++it) {
            int f = wv + 2 * it;               // 0..17
            if (f < 8) {
                int c = f >> 2, nt = f & 3;
                gload16(kbase + (size_t)(kt * 64 + nt * 16) * 64 + c * 32, &kf[p][f][0][0]);
            } else {
                int pnl = f - 8;               // 0..9
                int nt = pnl >> 1, c = pnl & 1;
                gload16(vbase + (size_t)nt * 16 * 4096 + kt * 64 + c * 32, &vf[p][pnl][0][0]);
            }
        }
    };

    int p = 0;
    stage(kt0, 0);
    __syncthreads();

    for (int kt = kt0; kt <= kt1; ++kt) {
        if (kt < kt1) stage(kt + 1, p ^ 1);

        short8 kfr[8];
        #pragma unroll
        for (int f = 0; f < 8; ++f)
            kfr[f] = *(const short8*)(&kf[p][f][lane][0]);

        #pragma unroll
        for (int rg = 0; rg < 2; ++rg) {
            f32x4 sacc[4] = {zero4, zero4, zero4, zero4};
            #pragma unroll
            for (int nt = 0; nt < 4; ++nt) {
                sacc[nt] = MFMA16(qa[rg][0], kfr[nt],     sacc[nt]);
                sacc[nt] = MFMA16(qa[rg][1], kfr[4 + nt], sacc[nt]);
            }
            if (kt == ktdiag) {
                int qg = r0 + wv * 32 + rg * 16 + quad * 4;
                #pragma unroll
                for (int nt = 0; nt < 4; ++nt)
                    #pragma unroll
                    for (int r = 0; r < 4; ++r) {
                        int key = kt * 64 + nt * 16 + n;
                        if (key > qg + r) sacc[nt][r] = -1e30f;
                    }
            }
            #pragma unroll
            for (int nt = 0; nt < 4; ++nt)
                #pragma unroll
                for (int r = 0; r < 4; ++r)
                    pbuf[wv][rg * 16 + quad * 4 + r][nt * 16 + n] = f2bf(__expf(sacc[nt][r]));
        }

        short8 vfr[10];
        #pragma unroll
        for (int pnl = 0; pnl < 10; ++pnl)
            vfr[pnl] = *(const short8*)(&vf[p][pnl][lane][0]);

        #pragma unroll
        for (int rg = 0; rg < 2; ++rg) {
            short8 pa0 = *(const short8*)(&pbuf[wv][rg * 16 + n][quad * 8]);
            short8 pa1 = *(const short8*)(&pbuf[wv][rg * 16 + n][32 + quad * 8]);
            #pragma unroll
            for (int nt = 0; nt < 5; ++nt) {
                oacc[rg][nt] = MFMA16(pa0, vfr[2 * nt],     oacc[rg][nt]);
                oacc[rg][nt] = MFMA16(pa1, vfr[2 * nt + 1], oacc[rg][nt]);
            }
        }

        __syncthreads();
        p ^= 1;
    }

    if (SPLIT) {
        #pragma unroll
        for (int rg = 0; rg < 2; ++rg)
            #pragma unroll
            for (int r = 0; r < 4; ++r) {
                int row = wv * 32 + rg * 16 + quad * 4 + r;
                #pragma unroll
                for (int nt = 0; nt < 4; ++nt)
                    dst[row * 64 + nt * 16 + n] = oacc[rg][nt][r];
                if (n == 0) dst[4096 + row] = oacc[rg][4][r];
            }
    } else {
        #pragma unroll
        for (int rg = 0; rg < 2; ++rg)
            #pragma unroll
            for (int r = 0; r < 4; ++r) {
                float l   = __shfl(oacc[rg][4][r], quad * 16, 64);
                float inv = 1.f / l;
                int q = r0 + wv * 32 + rg * 16 + quad * 4 + r;
                #pragma unroll
                for (int nt = 0; nt < 4; ++nt)
                    dst[(size_t)(b * 4096 + q) * 64 + nt * 16 + n] = oacc[rg][nt][r] * inv;
            }
    }
}

// Split-K: block -> (b, qtile64, chunk of 8 kt). 4 x 288 = 1152 blocks.
__global__ __launch_bounds__(128) void attn_part(
    const unsigned short* __restrict__ Q,
    const unsigned short* __restrict__ K,
    const unsigned short* __restrict__ Vt,
    float* __restrict__ Part)
{
    int id = blockIdx.x;
    int b  = id & 3;
    int t  = 287 - (id >> 2);              // heavy chunks first
    int g  = 0;
    while (4 * (g + 1) * (g + 2) <= t) ++g;
    int u  = t - 4 * g * (g + 1);
    int qt = 8 * g + u / (g + 1);
    int c  = u - (u / (g + 1)) * (g + 1);

    int r0  = qt * 64;
    int kt0 = c * 8;
    int kt1 = min(kt0 + 7, qt);

    float* dst = Part + (size_t)(b * 288 + t) * 4160;
    attn_body<1>(Q, K, Vt, dst, b, r0, qt, kt0, kt1);
}

// Monolithic fallback (ws too small).
__global__ __launch_bounds__(128) void attn_mono(
    const unsigned short* __restrict__ Q,
    const unsigned short* __restrict__ K,
    const unsigned short* __restrict__ Vt,
    float* __restrict__ out)
{
    int id = blockIdx.x;
    int qt = 63 - (id >> 2);
    int b  = id & 3;
    attn_body<0>(Q, K, Vt, out, b, qt * 64, qt, 0, qt);
}

// ---------------------------------------------------------------- combine
__global__ __launch_bounds__(256) void combine(
    const float* __restrict__ Part, float* __restrict__ out)
{
    int id = blockIdx.x;          // 256 = 4 b x 64 qt
    int b  = id & 3;
    int qt = id >> 2;
    int g  = qt >> 3;
    int nc = g + 1;
    int t0 = 4 * g * (g + 1) + (qt - 8 * g) * (g + 1);
    const float* P0 = Part + (size_t)(b * 288 + t0) * 4160;

    __shared__ float invden[64];
    int tid = threadIdx.x;
    if (tid < 64) {
        float den = 0.f;
        for (int c = 0; c < nc; ++c) den += P0[c * 4160 + 4096 + tid];
        invden[tid] = 1.f / den;
    }
    __syncthreads();

    #pragma unroll
    for (int i = 0; i < 16; ++i) {
        int e   = tid + i * 256;      // 0..4095
        int row = e >> 6;
        float acc = 0.f;
        for (int c = 0; c < nc; ++c) acc += P0[c * 4160 + e];
        out[((size_t)b * 4096 + qt * 64 + row) * 64 + (e & 63)] = acc * invden[row];
    }
}

// ---------------------------------------------------------------- launcher
extern "C" void kernel_launch(void* const* d_in, const int* in_sizes, int n_in,
                              void* d_out, int out_size, void* d_ws, size_t ws_size,
                              hipStream_t stream) {
    const float* x  = (const float*)d_in[0];
    const float* Wq = (const float*)d_in[1];
    const float* Wk = (const float*)d_in[2];
    const float* Wv = (const float*)d_in[3];
    float* outp = (float*)d_out;
    unsigned short* ws = (unsigned short*)d_ws;

    // ws (bf16 elems): Q 1M | K 1M | Vt 4*80*4096 | Wt 192K, then fp32 partials
    unsigned short* Qw  = ws;
    unsigned short* Kw  = ws + 1048576;
    unsigned short* Vtw = ws + 2097152;            // 1310720 elems
    unsigned short* Wt  = ws + 3407872;            // 196608 elems -> end 3604480

    size_t part_off = ((size_t)3604480 * 2 + 255) & ~(size_t)255;
    size_t need     = part_off + (size_t)4 * 288 * 4160 * 4;
    float* Part = (float*)((char*)d_ws + part_off);

    transpose_w<<<dim3(1792), dim3(256), 0, stream>>>(Wq, Wk, Wv, Wt, Vtw);
    proj_all<<<dim3(512), dim3(128), 0, stream>>>(x, Wt, Qw, Kw, Vtw);

    if (ws_size >= need) {
        attn_part<<<dim3(1152), dim3(128), 0, stream>>>(Qw, Kw, Vtw, Part);
        combine<<<dim3(256), dim3(256), 0, stream>>>(Part, outp);
    } else {
        attn_mono<<<dim3(256), dim3(128), 0, stream>>>(Qw, Kw, Vtw, outp);
    }
}

// Round 9
// 188.609 us; speedup vs baseline: 1.0357x; 1.0357x over previous
//
#include <hip/hip_runtime.h>

// SelfAttention: B=4, S=4096, E=1024, H=64, single head, causal, p=0.
// I/O fp32, internals bf16 MFMA.
// Round 9: proj staging made DMA-contiguous. W is pre-arranged in frag order
// in global memory (Ws) by transpose_w, so each W-panel stage is a contiguous
// 1KB global_load_lds; x staged as 4-row x 256B contiguous instrs with XOR
// chunk swizzle to kill readback bank conflicts. Attn (R7/R8) unchanged.

using short8 = __attribute__((ext_vector_type(8))) short;
using f32x4  = __attribute__((ext_vector_type(4))) float;

#define MFMA16(A, B, C) __builtin_amdgcn_mfma_f32_16x16x32_bf16((A), (B), (C), 0, 0, 0)

typedef const __attribute__((address_space(1))) void* gas_ptr;
typedef __attribute__((address_space(3))) void*       las_ptr;

__device__ __forceinline__ void gload16(const void* g, void* l) {
    // async global->LDS, 16B/lane, LDS dst = base + lane*16 (wave-uniform base)
    __builtin_amdgcn_global_load_lds((gas_ptr)g, (las_ptr)l, 16, 0, 0);
}

__device__ __forceinline__ unsigned short f2bf(float f) {
    unsigned u = __builtin_bit_cast(unsigned, f);
    u += 0x7fffu + ((u >> 16) & 1u);   // RNE
    return (unsigned short)(u >> 16);
}
__device__ __forceinline__ float bf2f(unsigned short u) {
    unsigned v = ((unsigned)u) << 16;
    return __builtin_bit_cast(float, v);
}

// ------------------------------------------------- W frag-order pack + Vt pad
// o < 196608: Ws[sk][mt][g][l][j] = bf16 W[mt][e][h], e = sk*64+c*32+quad*8+j,
// h = nt*16+n, g=(c,nt), l=(quad,n). Makes proj W staging contiguous per panel.
// o >= 196608: fill Vt rows 64..79 (row 64 = 1.0 ones-column, 65..79 = 0).
__global__ __launch_bounds__(256) void transpose_w(
    const float* __restrict__ Wq,
    const float* __restrict__ Wk,
    const float* __restrict__ Wv,
    unsigned short* __restrict__ Ws,
    unsigned short* __restrict__ Vt)
{
    int o = blockIdx.x * 256 + threadIdx.x;   // 196608 + 262144 total
    if (o < 196608) {
        int j    = o & 7;
        int l    = (o >> 3) & 63;
        int g    = (o >> 9) & 7;
        int rem  = o >> 12;        // sk*3 + mt
        int mt   = rem % 3;
        int sk   = rem / 3;
        int c    = g >> 2, nt = g & 3;
        int quad = l >> 4, n  = l & 15;
        int e    = sk * 64 + c * 32 + quad * 8 + j;
        int h    = nt * 16 + n;
        const float* W = (mt == 0) ? Wq : (mt == 1) ? Wk : Wv;
        Ws[o] = f2bf(W[e * 64 + h]);
    } else {
        int jj  = o - 196608;                 // 4 b x 16 rows x 4096
        int b   = jj >> 16;
        int rem = jj & 65535;
        int h   = 64 + (rem >> 12);
        int s   = rem & 4095;
        Vt[((size_t)(b * 80 + h)) * 4096 + s] = (h == 64) ? 0x3F80 : 0;
    }
}

// ---------------------------------------------------------------- projection
// 512 blocks x 128 thr (2 waves), 32 rows x 192 cols, K-loop 1024 step 64.
// Double-buffered; ALL DMA instructions contiguous: W panels 1KB each from
// frag-ordered Ws; x as 4-row x 256B instrs with XOR-4 chunk swizzle.
__global__ __launch_bounds__(128, 2) void proj_all(
    const float* __restrict__ x,             // [16384][1024] fp32
    const unsigned short* __restrict__ Ws,   // [16][3][8][64][8] bf16 frag-order
    unsigned short* __restrict__ Qo,         // [16384][64] bf16
    unsigned short* __restrict__ Ko,         // [16384][64] bf16
    unsigned short* __restrict__ Vto)        // [4][80][4096] bf16 (V^T, padded)
{
    const int m0   = blockIdx.x * 32;
    const int tid  = threadIdx.x;
    const int lane = tid & 63;
    const int wv   = tid >> 6;     // 0..1
    const int quad = lane >> 4;
    const int n    = lane & 15;

    __shared__ __align__(16) float xs[2][8][64][4];   // 16 KB (buf, panel, slot)
    __shared__ __align__(16) short wf[2][24][64][8];  // 48 KB

    const f32x4 zero4 = {0.f, 0.f, 0.f, 0.f};
    f32x4 acc[3][4];
    #pragma unroll
    for (int mt = 0; mt < 3; ++mt)
        #pragma unroll
        for (int nt = 0; nt < 4; ++nt) acc[mt][nt] = zero4;

    auto stage = [&](int k0, int p) {
        int sk = k0 >> 6;
        // x: 8 instrs (4/wave), instr i = rows m0+4i..+3, 256B/row, swizzled
        #pragma unroll
        for (int it = 0; it < 4; ++it) {
            int i     = wv + 2 * it;                 // 0..7
            int Rl    = 4 * i + (lane >> 4);         // local row 0..31
            int chunk = (lane & 15) ^ ((Rl & 3) << 2);
            gload16(x + (size_t)(m0 + Rl) * 1024 + k0 + chunk * 4, &xs[p][i][0][0]);
        }
        // W: 24 contiguous 1KB panels (12/wave) from frag-ordered Ws
        #pragma unroll
        for (int it = 0; it < 12; ++it) {
            int f = wv + 2 * it;                     // 0..23
            gload16(Ws + (((size_t)sk * 24 + f) << 9) + lane * 8, &wf[p][f][0][0]);
        }
    };

    int p = 0;
    stage(0, 0);
    __syncthreads();

    for (int k0 = 0; k0 < 1024; k0 += 64) {
        if (k0 < 960) stage(k0 + 64, p ^ 1);   // prefetch (drained at barrier)

        // A-frag readback with inverse swizzle
        int sub = n & 3, s = sub << 2;
        const float* xp = &xs[p][wv * 4 + (n >> 2)][0][0] + sub * 64;
        f32x4 u0 = *(const f32x4*)(xp + (((2 * quad)     ^ s) << 2));
        f32x4 u1 = *(const f32x4*)(xp + (((2 * quad + 1) ^ s) << 2));
        f32x4 u2 = *(const f32x4*)(xp + (((8 + 2 * quad) ^ s) << 2));
        f32x4 u3 = *(const f32x4*)(xp + (((9 + 2 * quad) ^ s) << 2));
        short8 a0, a1;
        #pragma unroll
        for (int j = 0; j < 4; ++j) {
            a0[j]     = (short)f2bf(u0[j]);
            a0[4 + j] = (short)f2bf(u1[j]);
            a1[j]     = (short)f2bf(u2[j]);
            a1[4 + j] = (short)f2bf(u3[j]);
        }

        #pragma unroll
        for (int mt = 0; mt < 3; ++mt)
            #pragma unroll
            for (int nt = 0; nt < 4; ++nt) {
                acc[mt][nt] = MFMA16(a0, *(const short8*)(&wf[p][mt * 8 + nt][lane][0]),     acc[mt][nt]);
                acc[mt][nt] = MFMA16(a1, *(const short8*)(&wf[p][mt * 8 + 4 + nt][lane][0]), acc[mt][nt]);
            }

        __syncthreads();   // drain prefetch DMA + protect buffers
        p ^= 1;
    }

    #pragma unroll
    for (int nt = 0; nt < 4; ++nt) {
        #pragma unroll
        for (int r = 0; r < 4; ++r) {
            int m = m0 + wv * 16 + quad * 4 + r;
            int h = nt * 16 + n;
            Qo[(size_t)m * 64 + h] = f2bf(acc[0][nt][r]);
            Ko[(size_t)m * 64 + h] = f2bf(acc[1][nt][r]);
            int b = m >> 12, s2 = m & 4095;
            Vto[((size_t)(b * 80 + h)) * 4096 + s2] = f2bf(acc[2][nt][r]);
        }
    }
}

// ---------------------------------------------------------------- attention
// (R7 structure, unchanged) 64-row Q-tile, 2 waves x 32 rows, double-buffered
// K/V staging, one barrier per kt. Fixed-max softmax, rowsum via ones-column.
template <int SPLIT>
__device__ __forceinline__ void attn_body(
    const unsigned short* __restrict__ Q,
    const unsigned short* __restrict__ K,
    const unsigned short* __restrict__ Vt,   // [4][80][4096], row 64 = ones
    float* __restrict__ dst,
    int b, int r0, int ktdiag, int kt0, int kt1)
{
    const int tid  = threadIdx.x;
    const int lane = tid & 63;
    const int wv   = tid >> 6;
    const int quad = lane >> 4;
    const int n    = lane & 15;

    __shared__ __align__(16) short kf[2][8][64][8];            // 16 KB
    __shared__ __align__(16) short vf[2][10][64][8];           // 20 KB
    __shared__ __align__(16) unsigned short pbuf[2][32][72];   // 9 KB

    short8 qa[2][2];
    #pragma unroll
    for (int rg = 0; rg < 2; ++rg) {
        const unsigned short* qp =
            Q + (size_t)(b * 4096 + r0 + wv * 32 + rg * 16 + n) * 64 + quad * 8;
        #pragma unroll
        for (int j = 0; j < 8; ++j) {
            qa[rg][0][j] = (short)f2bf(bf2f(qp[j])      * 0.125f);
            qa[rg][1][j] = (short)f2bf(bf2f(qp[32 + j]) * 0.125f);
        }
    }

    const f32x4 zero4 = {0.f, 0.f, 0.f, 0.f};
    f32x4 oacc[2][5];
    #pragma unroll
    for (int rg = 0; rg < 2; ++rg)
        #pragma unroll
        for (int nt = 0; nt < 5; ++nt) oacc[rg][nt] = zero4;

    const unsigned short* kbase = K  + ((size_t)b * 4096 + n) * 64 + quad * 8;
    const unsigned short* vbase = Vt + ((size_t)b * 80 + n) * 4096 + quad * 8;

    auto stage = [&](int kt, int p) {
        #pragma unroll
        for (int it = 0; it < 9; ++it) {
            int f = wv + 2 * it;               // 0..17
            if (f < 8) {
                int c = f >> 2, nt = f & 3;
                gload16(kbase + (size_t)(kt * 64 + nt * 16) * 64 + c * 32, &kf[p][f][0][0]);
            } else {
                int pnl = f - 8;               // 0..9
                int nt = pnl >> 1, c = pnl & 1;
                gload16(vbase + (size_t)nt * 16 * 4096 + kt * 64 + c * 32, &vf[p][pnl][0][0]);
            }
        }
    };

    int p = 0;
    stage(kt0, 0);
    __syncthreads();

    for (int kt = kt0; kt <= kt1; ++kt) {
        if (kt < kt1) stage(kt + 1, p ^ 1);

        short8 kfr[8];
        #pragma unroll
        for (int f = 0; f < 8; ++f)
            kfr[f] = *(const short8*)(&kf[p][f][lane][0]);

        #pragma unroll
        for (int rg = 0; rg < 2; ++rg) {
            f32x4 sacc[4] = {zero4, zero4, zero4, zero4};
            #pragma unroll
            for (int nt = 0; nt < 4; ++nt) {
                sacc[nt] = MFMA16(qa[rg][0], kfr[nt],     sacc[nt]);
                sacc[nt] = MFMA16(qa[rg][1], kfr[4 + nt], sacc[nt]);
            }
            if (kt == ktdiag) {
                int qg = r0 + wv * 32 + rg * 16 + quad * 4;
                #pragma unroll
                for (int nt = 0; nt < 4; ++nt)
                    #pragma unroll
                    for (int r = 0; r < 4; ++r) {
                        int key = kt * 64 + nt * 16 + n;
                        if (key > qg + r) sacc[nt][r] = -1e30f;
                    }
            }
            #pragma unroll
            for (int nt = 0; nt < 4; ++nt)
                #pragma unroll
                for (int r = 0; r < 4; ++r)
                    pbuf[wv][rg * 16 + quad * 4 + r][nt * 16 + n] = f2bf(__expf(sacc[nt][r]));
        }

        short8 vfr[10];
        #pragma unroll
        for (int pnl = 0; pnl < 10; ++pnl)
            vfr[pnl] = *(const short8*)(&vf[p][pnl][lane][0]);

        #pragma unroll
        for (int rg = 0; rg < 2; ++rg) {
            short8 pa0 = *(const short8*)(&pbuf[wv][rg * 16 + n][quad * 8]);
            short8 pa1 = *(const short8*)(&pbuf[wv][rg * 16 + n][32 + quad * 8]);
            #pragma unroll
            for (int nt = 0; nt < 5; ++nt) {
                oacc[rg][nt] = MFMA16(pa0, vfr[2 * nt],     oacc[rg][nt]);
                oacc[rg][nt] = MFMA16(pa1, vfr[2 * nt + 1], oacc[rg][nt]);
            }
        }

        __syncthreads();
        p ^= 1;
    }

    if (SPLIT) {
        #pragma unroll
        for (int rg = 0; rg < 2; ++rg)
            #pragma unroll
            for (int r = 0; r < 4; ++r) {
                int row = wv * 32 + rg * 16 + quad * 4 + r;
                #pragma unroll
                for (int nt = 0; nt < 4; ++nt)
                    dst[row * 64 + nt * 16 + n] = oacc[rg][nt][r];
                if (n == 0) dst[4096 + row] = oacc[rg][4][r];
            }
    } else {
        #pragma unroll
        for (int rg = 0; rg < 2; ++rg)
            #pragma unroll
            for (int r = 0; r < 4; ++r) {
                float l   = __shfl(oacc[rg][4][r], quad * 16, 64);
                float inv = 1.f / l;
                int q = r0 + wv * 32 + rg * 16 + quad * 4 + r;
                #pragma unroll
                for (int nt = 0; nt < 4; ++nt)
                    dst[(size_t)(b * 4096 + q) * 64 + nt * 16 + n] = oacc[rg][nt][r] * inv;
            }
    }
}

// Split-K: block -> (b, qtile64, chunk of 8 kt). 4 x 288 = 1152 blocks.
__global__ __launch_bounds__(128) void attn_part(
    const unsigned short* __restrict__ Q,
    const unsigned short* __restrict__ K,
    const unsigned short* __restrict__ Vt,
    float* __restrict__ Part)
{
    int id = blockIdx.x;
    int b  = id & 3;
    int t  = 287 - (id >> 2);              // heavy chunks first
    int g  = 0;
    while (4 * (g + 1) * (g + 2) <= t) ++g;
    int u  = t - 4 * g * (g + 1);
    int qt = 8 * g + u / (g + 1);
    int c  = u - (u / (g + 1)) * (g + 1);

    int r0  = qt * 64;
    int kt0 = c * 8;
    int kt1 = min(kt0 + 7, qt);

    float* dst = Part + (size_t)(b * 288 + t) * 4160;
    attn_body<1>(Q, K, Vt, dst, b, r0, qt, kt0, kt1);
}

// Monolithic fallback (ws too small).
__global__ __launch_bounds__(128) void attn_mono(
    const unsigned short* __restrict__ Q,
    const unsigned short* __restrict__ K,
    const unsigned short* __restrict__ Vt,
    float* __restrict__ out)
{
    int id = blockIdx.x;
    int qt = 63 - (id >> 2);
    int b  = id & 3;
    attn_body<0>(Q, K, Vt, out, b, qt * 64, qt, 0, qt);
}

// ---------------------------------------------------------------- combine
__global__ __launch_bounds__(256) void combine(
    const float* __restrict__ Part, float* __restrict__ out)
{
    int id = blockIdx.x;          // 256 = 4 b x 64 qt
    int b  = id & 3;
    int qt = id >> 2;
    int g  = qt >> 3;
    int nc = g + 1;
    int t0 = 4 * g * (g + 1) + (qt - 8 * g) * (g + 1);
    const float* P0 = Part + (size_t)(b * 288 + t0) * 4160;

    __shared__ float invden[64];
    int tid = threadIdx.x;
    if (tid < 64) {
        float den = 0.f;
        for (int c = 0; c < nc; ++c) den += P0[c * 4160 + 4096 + tid];
        invden[tid] = 1.f / den;
    }
    __syncthreads();

    #pragma unroll
    for (int i = 0; i < 16; ++i) {
        int e   = tid + i * 256;      // 0..4095
        int row = e >> 6;
        float acc = 0.f;
        for (int c = 0; c < nc; ++c) acc += P0[c * 4160 + e];
        out[((size_t)b * 4096 + qt * 64 + row) * 64 + (e & 63)] = acc * invden[row];
    }
}

// ---------------------------------------------------------------- launcher
extern "C" void kernel_launch(void* const* d_in, const int* in_sizes, int n_in,
                              void* d_out, int out_size, void* d_ws, size_t ws_size,
                              hipStream_t stream) {
    const float* x  = (const float*)d_in[0];
    const float* Wq = (const float*)d_in[1];
    const float* Wk = (const float*)d_in[2];
    const float* Wv = (const float*)d_in[3];
    float* outp = (float*)d_out;
    unsigned short* ws = (unsigned short*)d_ws;

    // ws (bf16 elems): Q 1M | K 1M | Vt 4*80*4096 | Ws 192K, then fp32 partials
    unsigned short* Qw  = ws;
    unsigned short* Kw  = ws + 1048576;
    unsigned short* Vtw = ws + 2097152;            // 1310720 elems
    unsigned short* Wsp = ws + 3407872;            // 196608 elems -> end 3604480

    size_t part_off = ((size_t)3604480 * 2 + 255) & ~(size_t)255;
    size_t need     = part_off + (size_t)4 * 288 * 4160 * 4;
    float* Part = (float*)((char*)d_ws + part_off);

    transpose_w<<<dim3(1792), dim3(256), 0, stream>>>(Wq, Wk, Wv, Wsp, Vtw);
    proj_all<<<dim3(512), dim3(128), 0, stream>>>(x, Wsp, Qw, Kw, Vtw);

    if (ws_size >= need) {
        attn_part<<<dim3(1152), dim3(128), 0, stream>>>(Qw, Kw, Vtw, Part);
        combine<<<dim3(256), dim3(256), 0, stream>>>(Part, outp);
    } else {
        attn_mono<<<dim3(256), dim3(128), 0, stream>>>(Qw, Kw, Vtw, outp);
    }
}